// Round 4
// baseline (1256.085 us; speedup 1.0000x reference)
//
#include <hip/hip_runtime.h>

#define N_NODES 10000
#define N_EDGES 160000
#define HID 128
#define NG 100
#define NF 64
#define NIO 4096     // NF*NF (w2 row stride)
#define NJ 8192      // HID * NF / 2? no: k(128) x o(64) = 8192 permuted columns
#define M_PAD 10240  // padded bf16-x rows (chunked GEMM may read past N_NODES)

typedef short bf16x8 __attribute__((ext_vector_type(8)));
typedef float f32x4 __attribute__((ext_vector_type(4)));

__device__ __forceinline__ unsigned short f2b(float f) {
    unsigned int u = __float_as_uint(f);
    u += 0x7fffu + ((u >> 16) & 1u);  // RNE
    return (unsigned short)(u >> 16);
}
__device__ __forceinline__ float b2f(unsigned short s) { return __uint_as_float((unsigned int)s << 16); }
__device__ __forceinline__ float b2f_lo(unsigned int u) { return __uint_as_float(u << 16); }
__device__ __forceinline__ float b2f_hi(unsigned int u) { return __uint_as_float(u & 0xffff0000u); }

// ---------------- degree ----------------
__global__ void deg_kernel(const int* __restrict__ dst, float* __restrict__ deg) {
    int e = blockIdx.x * 256 + threadIdx.x;
    if (e < N_EDGES) atomicAdd(&deg[dst[e]], 1.0f);
}
__global__ void invdeg_kernel(const float* __restrict__ deg, float* __restrict__ invd) {
    int n = blockIdx.x * 256 + threadIdx.x;
    if (n < N_NODES) invd[n] = 1.0f / fmaxf(deg[n], 1.0f);
}

// ---------------- x0 = relu(h @ lin0_w + b); f32 + split-bf16 mirrors ----------------
__global__ void lin0_kernel(const float* __restrict__ h, const float* __restrict__ w,
                            const float* __restrict__ b, float* __restrict__ x,
                            unsigned short* __restrict__ xh, unsigned short* __restrict__ xl) {
    int wv = threadIdx.x >> 6, l = threadIdx.x & 63;
    int n = blockIdx.x * 4 + wv;
    float h0 = h[n * HID + l];
    float h1 = h[n * HID + 64 + l];
    float acc = b[l];
#pragma unroll
    for (int i = 0; i < 64; ++i) {
        acc += __shfl(h0, i) * w[i * NF + l];
        acc += __shfl(h1, i) * w[(64 + i) * NF + l];
    }
    float v = fmaxf(acc, 0.0f);
    x[n * NF + l] = v;
    unsigned short hi = f2b(v);
    xh[n * NF + l] = hi;
    xl[n * NF + l] = f2b(v - b2f(hi));
}

// ---------------- hidden = relu(edge_attr @ w1 + b1), bf16 ----------------
__global__ void hidden_kernel(const float* __restrict__ ea, const float* __restrict__ w1,
                              const float* __restrict__ b1, unsigned short* __restrict__ hid) {
    __shared__ float ealds[2][NG];
    int sub = threadIdx.x >> 7, c = threadIdx.x & 127;
    int t = threadIdx.x;
    long e = (long)blockIdx.x * 2 + sub;
    if (t < 2 * NG) ealds[t / NG][t % NG] = ea[(long)blockIdx.x * 2 * NG + t];
    __syncthreads();
    float acc = b1[c];
#pragma unroll
    for (int k = 0; k < NG; ++k) acc += ealds[sub][k] * w1[k * HID + c];
    hid[e * HID + c] = f2b(fmaxf(acc, 0.0f));
}

// ---------------- w2pt[j*64+i] = split-bf16(w2[k(j)*4096 + i*64 + o(j)]), j=k*64+o in [0,8192) ----------------
__global__ void w2pt_kernel(const float* __restrict__ w2, unsigned short* __restrict__ wh,
                            unsigned short* __restrict__ wl) {
    int id = blockIdx.x * 256 + threadIdx.x;  // id = j*64 + i, over NJ*64 = 524288
    int i = id & 63, j = id >> 6;
    int k = j >> 6, o = j & 63;               // k in [0,128), o in [0,64)
    float v = w2[k * NIO + i * 64 + o];
    unsigned short hi = f2b(v);
    wh[id] = hi;
    wl[id] = f2b(v - b2f(hi));
}

// ---------------- xb2[n,o] = sum_i x[n,i] * b2[i*64+o]  (f32, exact) ----------------
__global__ void xb2_kernel(const float* __restrict__ x, const float* __restrict__ b2,
                           float* __restrict__ xb2) {
    int wv = threadIdx.x >> 6, l = threadIdx.x & 63;
    int n = blockIdx.x * 4 + wv;
    float xv = x[n * NF + l];
    float acc = 0.0f;
#pragma unroll
    for (int i = 0; i < 64; ++i) acc += __shfl(xv, i) * b2[i * 64 + l];
    xb2[n * NF + l] = acc;
}

// ---------------- y[r, j] = sum_i x[n0+r, i] * w2p[j, i]  (split-bf16 3-pass MFMA) ----------------
__launch_bounds__(256)
__global__ void ygemm_kernel(const unsigned short* __restrict__ xh, const unsigned short* __restrict__ xl,
                             const unsigned short* __restrict__ wh, const unsigned short* __restrict__ wl,
                             unsigned short* __restrict__ y, int n0) {
    __shared__ float stg[4][1024];  // per-wave private 4KB staging
    const int tid = threadIdx.x, wv = tid >> 6, l = tid & 63;
    const int grow = blockIdx.x * 128;  // chunk-local row base
    const int col0 = blockIdx.y * 128;  // in [0, 8192)
    const int wr = (wv >> 1) * 64, wc = (wv & 1) * 64;
    const long aoff = (long)(n0 + grow) * NF;
    const long boff = (long)col0 * NF;

    f32x4 acc[4][4] = {};
#pragma unroll
    for (int ks = 0; ks < 2; ++ks) {
        bf16x8 ah[4], al[4], bh[4], bl[4];
#pragma unroll
        for (int m = 0; m < 4; ++m) {
            long o = aoff + (wr + m * 16 + (l & 15)) * NF + ks * 32 + (l >> 4) * 8;
            ah[m] = *(const bf16x8*)(xh + o);
            al[m] = *(const bf16x8*)(xl + o);
        }
#pragma unroll
        for (int n = 0; n < 4; ++n) {
            long o = boff + (wc + n * 16 + (l & 15)) * NF + ks * 32 + (l >> 4) * 8;
            bh[n] = *(const bf16x8*)(wh + o);
            bl[n] = *(const bf16x8*)(wl + o);
        }
#pragma unroll
        for (int m = 0; m < 4; ++m)
#pragma unroll
            for (int n = 0; n < 4; ++n) {
                acc[m][n] = __builtin_amdgcn_mfma_f32_16x16x32_bf16(ah[m], bh[n], acc[m][n], 0, 0, 0);
                acc[m][n] = __builtin_amdgcn_mfma_f32_16x16x32_bf16(ah[m], bl[n], acc[m][n], 0, 0, 0);
                acc[m][n] = __builtin_amdgcn_mfma_f32_16x16x32_bf16(al[m], bh[n], acc[m][n], 0, 0, 0);
            }
    }

    float* s = stg[wv];
    int r8 = l >> 3, cg = l & 7;
#pragma unroll
    for (int m = 0; m < 4; ++m) {
#pragma unroll
        for (int n = 0; n < 4; ++n)
#pragma unroll
            for (int q = 0; q < 4; ++q)
                s[((l >> 4) * 4 + q) * 64 + n * 16 + (l & 15)] = acc[m][n][q];
        // wave-private staging: same-wave ds_write -> ds_read ordered via lgkmcnt
#pragma unroll
        for (int it = 0; it < 2; ++it) {
            int row = it * 8 + r8;
            const float* sr = s + row * 64 + cg * 8;
            unsigned int u[4];
#pragma unroll
            for (int p = 0; p < 4; ++p)
                u[p] = ((unsigned int)f2b(sr[2 * p + 1]) << 16) | f2b(sr[2 * p]);
            long R = grow + wr + m * 16 + row;  // chunk-local
            *(uint4*)(y + R * NJ + col0 + wc + cg * 8) = make_uint4(u[0], u[1], u[2], u[3]);
        }
    }
}

// ---------------- per-edge: msg = hid[e] . y[src[e]] (+xb2), atomic scatter to agg[dst] ----------------
__global__ void matvec_kernel(const unsigned short* __restrict__ y,
                              const unsigned short* __restrict__ hid,
                              const int* __restrict__ src, const int* __restrict__ dst,
                              const float* __restrict__ xb2, float* __restrict__ agg,
                              int n0, int n1) {
    int wv = threadIdx.x >> 6, l = threadIdx.x & 63;
    long e = (long)blockIdx.x * 4 + wv;
    int s = src[e];
    if (s < n0 || s >= n1) return;  // chunk filter (wave-uniform)
    int d = dst[e];
    int r8 = l >> 3;
    float hv0 = b2f(hid[e * HID + l]);       // lane l holds hid[e, l]
    float hv1 = b2f(hid[e * HID + 64 + l]);  // and hid[e, 64+l]
    const uint4* Y = (const uint4*)(y + (long)(s - n0) * NJ);
    float acc[8] = {0, 0, 0, 0, 0, 0, 0, 0};
#pragma unroll
    for (int t = 0; t < 16; ++t) {
        uint4 w = Y[t * 64 + l];  // covers k = 8t + r8, o = (l&7)*8 .. +8
        float hk = (t < 8) ? __shfl(hv0, r8 + 8 * t) : __shfl(hv1, r8 + 8 * t - 64);
        acc[0] += hk * b2f_lo(w.x);
        acc[1] += hk * b2f_hi(w.x);
        acc[2] += hk * b2f_lo(w.y);
        acc[3] += hk * b2f_hi(w.y);
        acc[4] += hk * b2f_lo(w.z);
        acc[5] += hk * b2f_hi(w.z);
        acc[6] += hk * b2f_lo(w.w);
        acc[7] += hk * b2f_hi(w.w);
    }
#pragma unroll
    for (int t = 0; t < 8; ++t) {
        acc[t] += __shfl_xor(acc[t], 8);
        acc[t] += __shfl_xor(acc[t], 16);
        acc[t] += __shfl_xor(acc[t], 32);
    }
    float v = acc[0];
    v = (r8 == 1) ? acc[1] : v;
    v = (r8 == 2) ? acc[2] : v;
    v = (r8 == 3) ? acc[3] : v;
    v = (r8 == 4) ? acc[4] : v;
    v = (r8 == 5) ? acc[5] : v;
    v = (r8 == 6) ? acc[6] : v;
    v = (r8 == 7) ? acc[7] : v;
    int o = (l & 7) * 8 + r8;
    v += xb2[(long)s * NF + o];
    atomicAdd(&agg[(long)d * NF + o], v);
}

// ---------------- x' = agg*inv_deg + x @ root_w + conv_b (+ optional split mirrors) ----------------
__global__ void combine_kernel(const float* __restrict__ x, const float* __restrict__ agg,
                               const float* __restrict__ invd, const float* __restrict__ rw,
                               const float* __restrict__ cb, float* __restrict__ xo,
                               unsigned short* __restrict__ xh, unsigned short* __restrict__ xl) {
    int wv = threadIdx.x >> 6, l = threadIdx.x & 63;
    int n = blockIdx.x * 4 + wv;
    float xv = x[n * NF + l];
    float acc = cb[l];
#pragma unroll
    for (int i = 0; i < 64; ++i) acc += __shfl(xv, i) * rw[i * NF + l];
    float v = agg[n * NF + l] * invd[n] + acc;
    xo[n * NF + l] = v;
    if (xh) {
        unsigned short hi = f2b(v);
        xh[n * NF + l] = hi;
        xl[n * NF + l] = f2b(v - b2f(hi));
    }
}

extern "C" void kernel_launch(void* const* d_in, const int* in_sizes, int n_in,
                              void* d_out, int out_size, void* d_ws, size_t ws_size,
                              hipStream_t stream) {
    const float* h = (const float*)d_in[0];
    const int* ei = (const int*)d_in[1];  // int inputs arrive as int32
    const float* ea = (const float*)d_in[3];
    const float* lin0_w = (const float*)d_in[5];
    const float* lin0_b = (const float*)d_in[6];
    const float* nn_w1 = (const float*)d_in[7];
    const float* nn_b1 = (const float*)d_in[8];
    const float* nn_w2 = (const float*)d_in[9];
    const float* nn_b2 = (const float*)d_in[10];
    const float* root_w = (const float*)d_in[11];
    const float* conv_b = (const float*)d_in[12];
    const int* srcIdx = ei;
    const int* dstIdx = ei + N_EDGES;

    // ---- tier selection: pick fewest node-chunks whose y-buffer fits ws ----
    const size_t fixed =
        (size_t)N_EDGES * HID * 2 +      // hid
        (size_t)NJ * NF * 2 * 2 +        // w2pt hi/lo (1MB each)
        (size_t)M_PAD * NF * 2 * 2 +     // x hi/lo mirrors
        (size_t)N_NODES * NF * 4 * 4 +   // xA, xB, agg, xb2
        (size_t)N_NODES * 4 * 2 +        // deg, invd
        16384;                           // alignment slack
    int nc = 0, CSn = 0, CSp = 0;
    for (int c = 1; c <= 16; c *= 2) {
        int csn = (N_NODES + c - 1) / c;
        int csp = ((csn + 127) / 128) * 128;
        if (fixed + (size_t)csp * NJ * 2 <= ws_size) { nc = c; CSn = csn; CSp = csp; break; }
    }
    if (nc == 0) {  // workspace too small even for 16 chunks (~70MB): signal zeros
        hipMemsetAsync(d_out, 0, (size_t)out_size * 4, stream);
        return;
    }

    char* ws = (char*)d_ws;
    size_t off = 0;
    auto alloc = [&](size_t bytes) {
        char* p = ws + off;
        off += (bytes + 255) & ~(size_t)255;
        return p;
    };
    unsigned short* y = (unsigned short*)alloc((size_t)CSp * NJ * 2);
    unsigned short* hid = (unsigned short*)alloc((size_t)N_EDGES * HID * 2);
    unsigned short* w2h = (unsigned short*)alloc((size_t)NJ * NF * 2);
    unsigned short* w2l = (unsigned short*)alloc((size_t)NJ * NF * 2);
    unsigned short* xh = (unsigned short*)alloc((size_t)M_PAD * NF * 2);
    unsigned short* xl = (unsigned short*)alloc((size_t)M_PAD * NF * 2);
    float* xA = (float*)alloc((size_t)N_NODES * NF * 4);
    float* xB = (float*)alloc((size_t)N_NODES * NF * 4);
    float* agg = (float*)alloc((size_t)N_NODES * NF * 4);
    float* xb2 = (float*)alloc((size_t)N_NODES * NF * 4);
    float* deg = (float*)alloc((size_t)N_NODES * 4);
    float* invd = (float*)alloc((size_t)N_NODES * 4);

    // ---- prep ----
    hipMemsetAsync(deg, 0, (size_t)N_NODES * 4, stream);
    deg_kernel<<<(N_EDGES + 255) / 256, 256, 0, stream>>>(dstIdx, deg);
    invdeg_kernel<<<(N_NODES + 255) / 256, 256, 0, stream>>>(deg, invd);
    lin0_kernel<<<N_NODES / 4, 256, 0, stream>>>(h, lin0_w, lin0_b, xA, xh, xl);
    hidden_kernel<<<N_EDGES / 2, 256, 0, stream>>>(ea, nn_w1, nn_b1, hid);
    w2pt_kernel<<<(NJ * NF) / 256, 256, 0, stream>>>(nn_w2, w2h, w2l);

    // ---- two conv applications (shared weights) ----
    for (int conv = 0; conv < 2; ++conv) {
        const float* xin = conv ? xB : xA;
        float* xout = conv ? (float*)d_out : xB;
        unsigned short* mh = conv ? nullptr : xh;  // conv1 output needs no bf16 mirror
        unsigned short* ml = conv ? nullptr : xl;

        xb2_kernel<<<N_NODES / 4, 256, 0, stream>>>(xin, nn_b2, xb2);
        hipMemsetAsync(agg, 0, (size_t)N_NODES * NF * 4, stream);
        for (int c = 0; c < nc; ++c) {
            int n0 = c * CSn;
            int n1 = n0 + CSn; if (n1 > N_NODES) n1 = N_NODES;
            if (n0 >= N_NODES) break;
            int gx = (n1 - n0 + 127) / 128;
            ygemm_kernel<<<dim3(gx, 64), 256, 0, stream>>>(xh, xl, w2h, w2l, y, n0);
            matvec_kernel<<<N_EDGES / 4, 256, 0, stream>>>(y, hid, srcIdx, dstIdx, xb2, agg, n0, n1);
        }
        combine_kernel<<<N_NODES / 4, 256, 0, stream>>>(xin, agg, invd, root_w, conv_b, xout, mh, ml);
    }
}